// Round 1
// baseline (270.445 us; speedup 1.0000x reference)
//
#include <hip/hip_runtime.h>

// LengthRegulator: expand x[B,L,D] along L per integer durations into out[B,T,D].
// B=64, L=256, D=512, T=max_length=1792 (fixed by setup_inputs).
// Output tuple: (out [B,T,D] f32, max_length scalar) -> d_out flat, f32.

#define BB 64
#define LL 256
#define DD 512
#define TT 1792
#define D4 (DD / 4)  // 128 float4 per row

__global__ __launch_bounds__(256) void length_regulator_kernel(
    const float4* __restrict__ x4,      // [B, L, D4]
    const int*    __restrict__ dur,     // [B, L]
    const int*    __restrict__ maxlen,  // [1]
    float*        __restrict__ out)     // [B*T*D + 1]
{
    __shared__ int cum[LL];
    const int tid = threadIdx.x;
    const int b   = blockIdx.y;

    // --- inclusive scan of durations for row b (Hillis-Steele, 8 steps) ---
    // ALPHA = 1.0 -> round(d * 1.0) == d
    cum[tid] = dur[b * LL + tid];
    __syncthreads();
    #pragma unroll
    for (int off = 1; off < LL; off <<= 1) {
        int v = (tid >= off) ? cum[tid - off] : 0;
        __syncthreads();
        cum[tid] += v;
        __syncthreads();
    }
    int total = cum[LL - 1];
    // all-zero row: d[0] = 1 -> cum[j] = 1 for all j
    if (total == 0) cum[tid] = 1;
    __syncthreads();
    total = cum[LL - 1];

    // --- expand: 2 groups x 128 lanes; each group copies one D-row per iter ---
    float4* out4 = (float4*)out;
    const int group  = tid >> 7;   // 0..1
    const int lane   = tid & 127;  // float4 index within row
    const int t_base = blockIdx.x * 16;

    #pragma unroll
    for (int j = 0; j < 8; ++j) {
        const int t = t_base + j * 2 + group;  // T = 112*16 exact, no bounds check
        float4 val = make_float4(0.f, 0.f, 0.f, 0.f);
        if (t < total) {
            // searchsorted(cum, t, side='right'): first idx with cum[idx] > t
            int lo = 0, hi = LL;
            while (lo < hi) {
                const int mid = (lo + hi) >> 1;
                if (cum[mid] <= t) lo = mid + 1; else hi = mid;
            }
            const int idx = (lo < LL - 1) ? lo : (LL - 1);
            val = x4[((size_t)b * LL + idx) * D4 + lane];
        }
        out4[((size_t)b * TT + t) * D4 + lane] = val;
    }

    // --- output 1: max_length as float, one thread writes it ---
    if (b == 0 && blockIdx.x == 0 && tid == 0) {
        out[(size_t)BB * TT * DD] = (float)maxlen[0];
    }
}

extern "C" void kernel_launch(void* const* d_in, const int* in_sizes, int n_in,
                              void* d_out, int out_size, void* d_ws, size_t ws_size,
                              hipStream_t stream) {
    const float4* x4  = (const float4*)d_in[0];
    const int*    dur = (const int*)d_in[1];
    const int*    ml  = (const int*)d_in[2];
    float*        out = (float*)d_out;

    dim3 grid(TT / 16, BB);  // (112, 64) blocks, 256 threads each
    length_regulator_kernel<<<grid, dim3(256), 0, stream>>>(x4, dur, ml, out);
}